// Round 6
// baseline (388.729 us; speedup 1.0000x reference)
//
#include <hip/hip_runtime.h>

typedef unsigned int uint32;
typedef unsigned short u16;
typedef float fx4 __attribute__((ext_vector_type(4)));
typedef uint32 u32x4 __attribute__((ext_vector_type(4)));

typedef const __attribute__((address_space(1))) void gvoid;
typedef __attribute__((address_space(3))) void lvoid;

#define MFMA_BF16_16x16x32(acc, a, b) \
  asm("v_mfma_f32_16x16x32_bf16 %0, %1, %2, %0" : "+v"(acc) : "v"(a), "v"(b))

#define WAIT_LGKM0() asm volatile("s_waitcnt lgkmcnt(0)" ::: "memory")
#define WAIT_VM0()   asm volatile("s_waitcnt vmcnt(0)" ::: "memory")
#define WAIT_VM2()   asm volatile("s_waitcnt vmcnt(2)" ::: "memory")
#define WAIT_VM3()   asm volatile("s_waitcnt vmcnt(3)" ::: "memory")
#define WAIT_VM4()   asm volatile("s_waitcnt vmcnt(4)" ::: "memory")
#define WAIT_VM6()   asm volatile("s_waitcnt vmcnt(6)" ::: "memory")
#define SFENCE()     __builtin_amdgcn_sched_barrier(0)
#define BARRIER()    do { __builtin_amdgcn_s_barrier(); asm volatile("" ::: "memory"); } while (0)

__device__ __forceinline__ u16 f2bf_rne(float f) {
  uint32 u = __builtin_bit_cast(uint32, f);
  u += 0x7FFFu + ((u >> 16) & 1u);
  return (u16)(u >> 16);
}

__device__ __forceinline__ uint32 cvt_pk_bf16(float lo, float hi) {
  uint32 r;
  asm("v_cvt_pk_bf16_f32 %0, %1, %2" : "=v"(r) : "v"(lo), "v"(hi));
  return r;
}

// ---------------------------------------------------------------------------
// x (fp32) -> bf16
// ---------------------------------------------------------------------------
__global__ __launch_bounds__(256) void cvtx_kernel(const float* __restrict__ x,
                                                   u16* __restrict__ xb) {
  const int i = blockIdx.x * 256 + threadIdx.x;
  float4 v = ((const float4*)x)[i];
  ushort4 o;
  o.x = f2bf_rne(v.x);
  o.y = f2bf_rne(v.y);
  o.z = f2bf_rne(v.z);
  o.w = f2bf_rne(v.w);
  ((ushort4*)xb)[i] = o;
}

// ---------------------------------------------------------------------------
// decode body: dec[t,r,d] = scales[t]*0.25 * sum_k cw[idx[t,r,k], d] (bf16)
// ---------------------------------------------------------------------------
__device__ __forceinline__ void decode_body(
    int bid, const float* __restrict__ cw, const int* __restrict__ indices,
    const float* __restrict__ scales, u16* __restrict__ dec) {
  const int tid = threadIdx.x;
#pragma unroll 1
  for (int rr = 0; rr < 16; ++rr) {
    const int row = bid * 16 + rr;       // t*512 + r
    const int t = row >> 9;
    const int* ip = indices + (size_t)row * 4;
    const float* c0 = cw + (size_t)ip[0] * 4096;
    const float* c1 = cw + (size_t)ip[1] * 4096;
    const float* c2 = cw + (size_t)ip[2] * 4096;
    const float* c3 = cw + (size_t)ip[3] * 4096;
    const float s = scales[t] * 0.25f;
    u16* orow = dec + (size_t)row * 4096;
#pragma unroll
    for (int j = 0; j < 4; ++j) {
      const int d = j * 1024 + tid * 4;
      float4 a = *(const float4*)(c0 + d);
      float4 b = *(const float4*)(c1 + d);
      float4 c = *(const float4*)(c2 + d);
      float4 e = *(const float4*)(c3 + d);
      ushort4 o;
      o.x = f2bf_rne((a.x + b.x + c.x + e.x) * s);
      o.y = f2bf_rne((a.y + b.y + c.y + e.y) * s);
      o.z = f2bf_rne((a.z + b.z + c.z + e.z) * s);
      o.w = f2bf_rne((a.w + b.w + c.w + e.w) * s);
      *(ushort4*)(orow + d) = o;
    }
  }
}

// ---------------------------------------------------------------------------
// Fused: blocks [0,256) decode; blocks [256,1280) z[t] = x_bf16 @ rot[t]^T.
// GEMM: per-t M=512,N=4096,K=4096; 128x128 tile, BK=32, 4 waves, 16 MFMA/step.
// LDS per buffer: A,B each [128 rows][4 slots of 16B] with slot-XOR
// s = k_chunk ^ ((row>>1)&3) -> ds_read_b128 frag reads conflict-free
// (verified 0 conflicts in round 5). 32 KB total -> 3 blocks/CU (12 waves)
// for cross-block latency hiding. A staged via global_load_lds with
// pre-swizzled SOURCE; B (fp32 rot) reg-staged -> cvt_pk_bf16 -> swizzled
// ds_write. Depth-2 B prefetch; counted vmcnt (6/4) - never 0 in the loop.
// ---------------------------------------------------------------------------
__global__ __launch_bounds__(256, 3) void fused_z_decode_kernel(
    const u16* __restrict__ Xb,    // [512][4096] bf16
    const float* __restrict__ rot, // [8][4096][4096] fp32
    u16* __restrict__ Z,           // [8][512][4096] bf16
    const float* __restrict__ cw, const int* __restrict__ indices,
    const float* __restrict__ scales, u16* __restrict__ dec) {
  __shared__ char sA[16384];      // 2 bufs x [128][64B]
  __shared__ char sB[16384];

  const int bid = blockIdx.x;
  if (bid < 256) {
    decode_body(bid, cw, indices, scales, dec);
    return;
  }
  const int lb = bid - 256;
  const int swz = ((lb & 7) << 7) | (lb >> 3);  // XCD-chunked (1024 % 8 == 0)
  const int t = swz >> 7;
  const int rem = swz & 127;
  const int nb = rem >> 2, mb = rem & 3;        // mb-sharers of B-panel adjacent
  const float* Bt = rot + ((size_t)t << 24);
  u16* Ct = Z + ((size_t)t << 21);
  const int aRow0 = mb << 7, bCol0 = nb << 7;
  const int tid = threadIdx.x;
  const int wv = tid >> 6, ln = tid & 63;
  const int lr = ln & 15, lk = ln >> 4;
  const int wr = wv >> 1, wc = wv & 1;

  fx4 acc[4][4] = {};

  // ---- A staging: source pre-swizzle (16B chunk permute within 64B row)
  const u16* Asrc = Xb + (size_t)(aRow0 + (ln >> 2)) * 4096 +
                    (((ln & 3) ^ ((ln >> 3) & 3)) << 3);
  // ---- B staging (reg): row = tid>>1, k-half h = tid&1 (16 fp32)
  const float* Bsrc = Bt + (size_t)(bCol0 + (tid >> 1)) * 4096 + (tid & 1) * 16;
  const int bds = (tid >> 1) * 64 + ((((tid & 1) << 1) ^ ((tid >> 2) & 3)) << 4);
  // ---- frag read offsets: slot-XOR folded into per-lane constant
  const int gr = (lr >> 1) & 3;
  const int aof = (wr * 64 + lr) * 64 + ((lk ^ gr) << 4);  // + m*1024
  const int bof = (wc * 64 + lr) * 64 + ((lk ^ gr) << 4);  // + n*1024

#define STAGE_A_Z(dbuf, kofs)                                                 \
  _Pragma("unroll")                                                           \
  for (int c = 0; c < 2; ++c)                                                 \
    __builtin_amdgcn_global_load_lds(                                         \
        (gvoid*)(Asrc + (size_t)((c * 4 + wv) << 4) * 4096 + (kofs)),         \
        (lvoid*)(sA + (dbuf) * 8192 + c * 4096 + (wv << 10) + ln * 16),       \
        16, 0, 0)

#define LOADB(p, kofs)                                                        \
  do {                                                                        \
    const float* bp_ = Bsrc + (kofs);                                         \
    p[0] = *(const float4*)(bp_ + 0);                                         \
    p[1] = *(const float4*)(bp_ + 4);                                         \
    p[2] = *(const float4*)(bp_ + 8);                                         \
    p[3] = *(const float4*)(bp_ + 12);                                        \
  } while (0)

#define PACK_B(p, dst)                                                        \
  do {                                                                        \
    u32x4 w_;                                                                 \
    w_[0] = cvt_pk_bf16(p[0].x, p[0].y); w_[1] = cvt_pk_bf16(p[0].z, p[0].w); \
    w_[2] = cvt_pk_bf16(p[1].x, p[1].y); w_[3] = cvt_pk_bf16(p[1].z, p[1].w); \
    *(u32x4*)((dst) + bds) = w_;                                              \
    w_[0] = cvt_pk_bf16(p[2].x, p[2].y); w_[1] = cvt_pk_bf16(p[2].z, p[2].w); \
    w_[2] = cvt_pk_bf16(p[3].x, p[3].y); w_[3] = cvt_pk_bf16(p[3].z, p[3].w); \
    *(u32x4*)((dst) + (bds ^ 16)) = w_;                                       \
  } while (0)

#define COMPUTE(dIdx)                                                         \
  do {                                                                        \
    const char* pA_ = sA + (dIdx) * 8192;                                     \
    const char* pB_ = sB + (dIdx) * 8192;                                     \
    u32x4 af[4], bf[4];                                                       \
    _Pragma("unroll")                                                         \
    for (int m = 0; m < 4; ++m) {                                             \
      af[m] = *(const u32x4*)(pA_ + aof + m * 1024);                          \
      bf[m] = *(const u32x4*)(pB_ + bof + m * 1024);                          \
    }                                                                         \
    WAIT_LGKM0();                                                             \
    SFENCE();                                                                 \
    __builtin_amdgcn_s_setprio(1);                                            \
    _Pragma("unroll")                                                         \
    for (int m = 0; m < 4; ++m)                                               \
      _Pragma("unroll")                                                       \
      for (int n = 0; n < 4; ++n)                                             \
        MFMA_BF16_16x16x32(acc[m][n], af[m], bf[n]);                          \
    __builtin_amdgcn_s_setprio(0);                                            \
    SFENCE();                                                                 \
  } while (0)

  float4 pa[4], pb[4];

  // ---- prologue: A(0)->buf0, B(0)->pa->pack->buf0, B(1)->pb in flight ----
  STAGE_A_Z(0, 0);
  LOADB(pa, 0);
  WAIT_VM0();
  PACK_B(pa, sB);
  LOADB(pb, 32);                  // 4 outstanding across the barrier
  WAIT_LGKM0();
  BARRIER();

#pragma unroll 1
  for (int kt2 = 0; kt2 < 128; kt2 += 2) {
    const bool more = (kt2 < 126);
    // ---- even kt = kt2: compute buf0; A(kt+1)->buf1; load pa = B(kt+2) ----
    STAGE_A_Z(1, (kt2 + 1) << 5);
    if (more) LOADB(pa, (kt2 + 2) << 5);
    COMPUTE(0);
    if (more) {
      WAIT_VM6();                 // pb = B(kt2+1) regs ready (2 DMA + 4 pa newer)
      PACK_B(pb, sB + 8192);
      WAIT_VM4();                 // A(kt2+1) DMA done; pa stays in flight
    } else {
      WAIT_VM2();
      PACK_B(pb, sB + 8192);
      WAIT_VM0();
    }
    WAIT_LGKM0();
    BARRIER();
    // ---- odd kt = kt2+1: compute buf1; A(kt+1)->buf0; load pb = B(kt+2) ----
    if (more) {
      STAGE_A_Z(0, (kt2 + 2) << 5);
      LOADB(pb, (kt2 + 3) << 5);
    }
    COMPUTE(1);
    if (more) {
      WAIT_VM6();                 // pa = B(kt2+2) regs ready
      PACK_B(pa, sB);
      WAIT_VM4();
      WAIT_LGKM0();
      BARRIER();
    }
  }

  // C/D layout: col = lane&15, row = (lane>>4)*4 + j
#pragma unroll
  for (int m = 0; m < 4; ++m) {
    const int r0 = aRow0 + wr * 64 + m * 16 + lk * 4;
#pragma unroll
    for (int n = 0; n < 4; ++n) {
      const int col = bCol0 + wc * 64 + n * 16 + lr;
#pragma unroll
      for (int j = 0; j < 4; ++j)
        Ct[(size_t)(r0 + j) * 4096 + col] = f2bf_rne(acc[m][n][j]);
    }
  }
#undef STAGE_A_Z
#undef LOADB
#undef PACK_B
#undef COMPUTE
}

// ---------------------------------------------------------------------------
// out[n, t*512+r] = sum_d z[t,n,d]*dec[t,r,d] + bias. 128x64 tile, BK=32.
// Triple-buffered depth-2 pipeline, counted vmcnt(3). Same slot-XOR swizzle
// (source-side for global_load_lds, per-lane constant on frag reads).
// ---------------------------------------------------------------------------
__global__ __launch_bounds__(256, 2) void gemm_out_kernel(
    const u16* __restrict__ Z,    // [8][512][4096]
    const u16* __restrict__ Dec,  // [8][512][4096]
    const float* __restrict__ bias,
    float* __restrict__ out) {    // [512][4096]
  __shared__ char sm[36864];      // 3 bufs x (A 8KB + B 4KB)
  const int lb = blockIdx.x;
  const int swz = ((lb & 7) << 5) | (lb >> 3);  // 256 % 8 == 0
  const int t = swz >> 5;
  const int rem = swz & 31;
  const int nb = rem >> 2, mb = rem & 3;
  const u16* At = Z + ((size_t)t << 21);
  const u16* Bt = Dec + ((size_t)t << 21);
  const int aRow0 = mb << 7, bCol0 = nb << 6;
  const int tid = threadIdx.x;
  const int wv = tid >> 6, ln = tid & 63;
  const int lr = ln & 15, lk = ln >> 4;
  const int wr = wv >> 1, wc = wv & 1;

  fx4 acc[4][2] = {};

  const int kswz = (((tid & 3) ^ ((tid >> 3) & 3)) << 3);
  const u16* Asrc = At + (size_t)(aRow0 + (tid >> 2)) * 4096 + kswz;
  const u16* Bsrc = Bt + (size_t)(bCol0 + (tid >> 2)) * 4096 + kswz;
  const int gr = (lr >> 1) & 3;
  const int aof = (wr * 64 + lr) * 64 + ((lk ^ gr) << 4);          // + m*1024
  const int bof = 8192 + (wc * 32 + lr) * 64 + ((lk ^ gr) << 4);   // + n*1024

#define STAGE_O(buf, kofs)                                                   \
  do {                                                                       \
    _Pragma("unroll")                                                        \
    for (int c = 0; c < 2; ++c)                                              \
      __builtin_amdgcn_global_load_lds(                                      \
          (gvoid*)(Asrc + (size_t)(c << 6) * 4096 + (kofs)),                 \
          (lvoid*)((buf) + c * 4096 + tid * 16), 16, 0, 0);                  \
    __builtin_amdgcn_global_load_lds((gvoid*)(Bsrc + (kofs)),                \
                                     (lvoid*)((buf) + 8192 + tid * 16), 16,  \
                                     0, 0);                                  \
  } while (0)

  char* b0 = sm;
  char* b1 = sm + 12288;
  char* b2 = sm + 24576;
  STAGE_O(b0, 0);
  STAGE_O(b1, 32);
  WAIT_VM3();                     // first stage (3 ops) complete
  BARRIER();

#pragma unroll 1
  for (int kt = 0; kt < 128; ++kt) {
    if (kt + 2 < 128) STAGE_O(b2, (kt + 2) << 5);
    u32x4 af[4], bf[2];
#pragma unroll
    for (int m = 0; m < 4; ++m)
      af[m] = *(const u32x4*)(b0 + aof + m * 1024);
#pragma unroll
    for (int n = 0; n < 2; ++n)
      bf[n] = *(const u32x4*)(b0 + bof + n * 1024);
    WAIT_LGKM0();
    SFENCE();
#pragma unroll
    for (int m = 0; m < 4; ++m)
#pragma unroll
      for (int n = 0; n < 2; ++n)
        MFMA_BF16_16x16x32(acc[m][n], af[m], bf[n]);
    if (kt + 2 < 128) {
      WAIT_VM3();                 // oldest stage (kt+1's buffer) complete
    } else {
      WAIT_VM0();
    }
    BARRIER();
    char* tmp = b0; b0 = b1; b1 = b2; b2 = tmp;
  }

#pragma unroll
  for (int n = 0; n < 2; ++n) {
    const int colg = (t << 9) + bCol0 + wc * 32 + n * 16 + lr;
    const float bv = bias[colg];
#pragma unroll
    for (int m = 0; m < 4; ++m) {
      const int r0 = aRow0 + wr * 64 + m * 16 + lk * 4;
#pragma unroll
      for (int j = 0; j < 4; ++j)
        out[(size_t)(r0 + j) * 4096 + colg] = acc[m][n][j] + bv;
    }
  }
#undef STAGE_O
}

// ---------------------------------------------------------------------------
extern "C" void kernel_launch(void* const* d_in, const int* in_sizes, int n_in,
                              void* d_out, int out_size, void* d_ws, size_t ws_size,
                              hipStream_t stream) {
  const float* x       = (const float*)d_in[0];   // [512][4096]
  const float* cw      = (const float*)d_in[1];   // [16384][4096]
  const int*   indices = (const int*)d_in[2];     // [8][512][4]
  const float* rot     = (const float*)d_in[3];   // [8][4096][4096]
  const float* scales  = (const float*)d_in[4];   // [8]
  const float* bias    = (const float*)d_in[5];   // [4096]
  float* out = (float*)d_out;
  char* ws = (char*)d_ws;

  u16* xb  = (u16*)(ws);                          // 4 MiB
  u16* dec = (u16*)(ws + ((size_t)4 << 20));      // 32 MiB
  u16* z   = (u16*)(ws + ((size_t)36 << 20));     // 32 MiB

  cvtx_kernel<<<dim3(2048), dim3(256), 0, stream>>>(x, xb);
  fused_z_decode_kernel<<<dim3(1280), dim3(256), 0, stream>>>(
      xb, rot, z, cw, indices, scales, dec);
  gemm_out_kernel<<<dim3(256), dim3(256), 0, stream>>>(z, dec, bias, out);
}

// Round 7
// 350.609 us; speedup vs baseline: 1.1087x; 1.1087x over previous
//
#include <hip/hip_runtime.h>

typedef unsigned int uint32;
typedef unsigned short u16;
typedef float fx4 __attribute__((ext_vector_type(4)));
typedef uint32 u32x4 __attribute__((ext_vector_type(4)));
typedef uint32 u32x2 __attribute__((ext_vector_type(2)));

typedef const __attribute__((address_space(1))) void gvoid;
typedef __attribute__((address_space(3))) void lvoid;

#define MFMA_BF16_16x16x32(acc, a, b) \
  asm("v_mfma_f32_16x16x32_bf16 %0, %1, %2, %0" : "+v"(acc) : "v"(a), "v"(b))

#define WAIT_LGKM0() asm volatile("s_waitcnt lgkmcnt(0)" ::: "memory")
#define WAIT_VM0()   asm volatile("s_waitcnt vmcnt(0)" ::: "memory")
#define WAIT_VM2()   asm volatile("s_waitcnt vmcnt(2)" ::: "memory")
#define WAIT_VM3()   asm volatile("s_waitcnt vmcnt(3)" ::: "memory")
#define WAIT_VM4()   asm volatile("s_waitcnt vmcnt(4)" ::: "memory")
#define WAIT_VM6()   asm volatile("s_waitcnt vmcnt(6)" ::: "memory")
#define SFENCE()     __builtin_amdgcn_sched_barrier(0)
#define BARRIER()    do { __builtin_amdgcn_s_barrier(); asm volatile("" ::: "memory"); } while (0)

__device__ __forceinline__ u16 f2bf_rne(float f) {
  uint32 u = __builtin_bit_cast(uint32, f);
  u += 0x7FFFu + ((u >> 16) & 1u);
  return (u16)(u >> 16);
}

__device__ __forceinline__ uint32 cvt_pk_bf16(float lo, float hi) {
  uint32 r;
  asm("v_cvt_pk_bf16_f32 %0, %1, %2" : "=v"(r) : "v"(lo), "v"(hi));
  return r;
}

// ---------------------------------------------------------------------------
// x (fp32) -> bf16
// ---------------------------------------------------------------------------
__global__ __launch_bounds__(256) void cvtx_kernel(const float* __restrict__ x,
                                                   u16* __restrict__ xb) {
  const int i = blockIdx.x * 256 + threadIdx.x;
  float4 v = ((const float4*)x)[i];
  ushort4 o;
  o.x = f2bf_rne(v.x);
  o.y = f2bf_rne(v.y);
  o.z = f2bf_rne(v.z);
  o.w = f2bf_rne(v.w);
  ((ushort4*)xb)[i] = o;
}

// ---------------------------------------------------------------------------
// decode body: dec[t,r,d] = scales[t]*0.25 * sum_k cw[idx[t,r,k], d] (bf16)
// ---------------------------------------------------------------------------
__device__ __forceinline__ void decode_body(
    int bid, const float* __restrict__ cw, const int* __restrict__ indices,
    const float* __restrict__ scales, u16* __restrict__ dec) {
  const int tid = threadIdx.x;
#pragma unroll 1
  for (int rr = 0; rr < 16; ++rr) {
    const int row = bid * 16 + rr;       // t*512 + r
    const int t = row >> 9;
    const int* ip = indices + (size_t)row * 4;
    const float* c0 = cw + (size_t)ip[0] * 4096;
    const float* c1 = cw + (size_t)ip[1] * 4096;
    const float* c2 = cw + (size_t)ip[2] * 4096;
    const float* c3 = cw + (size_t)ip[3] * 4096;
    const float s = scales[t] * 0.25f;
    u16* orow = dec + (size_t)row * 4096;
#pragma unroll
    for (int j = 0; j < 4; ++j) {
      const int d = j * 1024 + tid * 4;
      float4 a = *(const float4*)(c0 + d);
      float4 b = *(const float4*)(c1 + d);
      float4 c = *(const float4*)(c2 + d);
      float4 e = *(const float4*)(c3 + d);
      ushort4 o;
      o.x = f2bf_rne((a.x + b.x + c.x + e.x) * s);
      o.y = f2bf_rne((a.y + b.y + c.y + e.y) * s);
      o.z = f2bf_rne((a.z + b.z + c.z + e.z) * s);
      o.w = f2bf_rne((a.w + b.w + c.w + e.w) * s);
      *(ushort4*)(orow + d) = o;
    }
  }
}

// ---------------------------------------------------------------------------
// Fused: blocks [0,256) decode; blocks [256,1280) z[t] = x_bf16 @ rot[t]^T.
// GEMM: per-t M=512,N=4096,K=4096; 128x128 tile, BK=32, 4 waves, 16 MFMA/step.
// LDS per buffer: A,B each [128 rows][4 slots of 16B], slot s holds k-chunk
// s ^ ((row>>1)&3) -> frag ds_read_b128 conflict-free (verified 0, round 5).
// B global loads FULLY 128B-COALESCED: instr j reads 8 rows x 128B contiguous
// (row = wv*32 + (ln>>3) + 8j, 16B chunk c = ln&7) -- fixes the 8x VMEM
// transaction inflation of the old 32-rows-per-instr pattern. Pack ->
// 4x ds_write_b64 into the swizzled slots. vmcnt schedule (4 B + 2 A per
// step, VM6/VM4 steady, never 0 mid-loop) identical to round 6.
// ---------------------------------------------------------------------------
__global__ __launch_bounds__(256, 3) void fused_z_decode_kernel(
    const u16* __restrict__ Xb,    // [512][4096] bf16
    const float* __restrict__ rot, // [8][4096][4096] fp32
    u16* __restrict__ Z,           // [8][512][4096] bf16
    const float* __restrict__ cw, const int* __restrict__ indices,
    const float* __restrict__ scales, u16* __restrict__ dec) {
  __shared__ char sA[16384];      // 2 bufs x [128][64B]
  __shared__ char sB[16384];

  const int bid = blockIdx.x;
  if (bid < 256) {
    decode_body(bid, cw, indices, scales, dec);
    return;
  }
  const int lb = bid - 256;
  const int swz = ((lb & 7) << 7) | (lb >> 3);  // XCD-chunked (1024 % 8 == 0)
  const int t = swz >> 7;
  const int rem = swz & 127;
  const int nb = rem >> 2, mb = rem & 3;        // mb-sharers of B-panel adjacent
  const float* Bt = rot + ((size_t)t << 24);
  u16* Ct = Z + ((size_t)t << 21);
  const int aRow0 = mb << 7, bCol0 = nb << 7;
  const int tid = threadIdx.x;
  const int wv = tid >> 6, ln = tid & 63;
  const int lr = ln & 15, lk = ln >> 4;
  const int wr = wv >> 1, wc = wv & 1;

  fx4 acc[4][4] = {};

  // ---- A staging: source pre-swizzle (16B chunk permute within 64B row)
  const u16* Asrc = Xb + (size_t)(aRow0 + (ln >> 2)) * 4096 +
                    (((ln & 3) ^ ((ln >> 3) & 3)) << 3);
  // ---- B staging (reg, coalesced): instr j: rows R0+8j, chunk c = ln&7
  const int R0 = wv * 32 + (ln >> 3);
  const int cB = ln & 7;
  const float* Bsrc = Bt + (size_t)(bCol0 + R0) * 4096 + cB * 4;
  // swizzled LDS write base: slot (c>>1)^((R0>>1)&3) (j-independent: rows +8)
  const int bwr = R0 * 64 + ((((cB >> 1) ^ ((R0 >> 1) & 3)) << 4)) + ((cB & 1) << 3);
  // ---- frag read offsets: slot-XOR folded into per-lane constant
  const int gr = (lr >> 1) & 3;
  const int aof = (wr * 64 + lr) * 64 + ((lk ^ gr) << 4);  // + m*1024
  const int bof = (wc * 64 + lr) * 64 + ((lk ^ gr) << 4);  // + n*1024

#define STAGE_A_Z(dbuf, kofs)                                                 \
  _Pragma("unroll")                                                           \
  for (int c = 0; c < 2; ++c)                                                 \
    __builtin_amdgcn_global_load_lds(                                         \
        (gvoid*)(Asrc + (size_t)((c * 4 + wv) << 4) * 4096 + (kofs)),         \
        (lvoid*)(sA + (dbuf) * 8192 + c * 4096 + (wv << 10) + ln * 16),       \
        16, 0, 0)

#define LOADB(p, kofs)                                                        \
  do {                                                                        \
    const float* bp_ = Bsrc + (kofs);                                         \
    p[0] = *(const float4*)(bp_);                                             \
    p[1] = *(const float4*)(bp_ + 8 * 4096);                                  \
    p[2] = *(const float4*)(bp_ + 16 * 4096);                                 \
    p[3] = *(const float4*)(bp_ + 24 * 4096);                                 \
  } while (0)

#define PACK_B(p, dst)                                                        \
  do {                                                                        \
    u32x2 w_;                                                                 \
    w_[0] = cvt_pk_bf16(p[0].x, p[0].y); w_[1] = cvt_pk_bf16(p[0].z, p[0].w); \
    *(u32x2*)((dst) + bwr) = w_;                                              \
    w_[0] = cvt_pk_bf16(p[1].x, p[1].y); w_[1] = cvt_pk_bf16(p[1].z, p[1].w); \
    *(u32x2*)((dst) + bwr + 512) = w_;                                        \
    w_[0] = cvt_pk_bf16(p[2].x, p[2].y); w_[1] = cvt_pk_bf16(p[2].z, p[2].w); \
    *(u32x2*)((dst) + bwr + 1024) = w_;                                       \
    w_[0] = cvt_pk_bf16(p[3].x, p[3].y); w_[1] = cvt_pk_bf16(p[3].z, p[3].w); \
    *(u32x2*)((dst) + bwr + 1536) = w_;                                       \
  } while (0)

#define COMPUTE(dIdx)                                                         \
  do {                                                                        \
    const char* pA_ = sA + (dIdx) * 8192;                                     \
    const char* pB_ = sB + (dIdx) * 8192;                                     \
    u32x4 af[4], bf[4];                                                       \
    _Pragma("unroll")                                                         \
    for (int m = 0; m < 4; ++m) {                                             \
      af[m] = *(const u32x4*)(pA_ + aof + m * 1024);                          \
      bf[m] = *(const u32x4*)(pB_ + bof + m * 1024);                          \
    }                                                                         \
    WAIT_LGKM0();                                                             \
    SFENCE();                                                                 \
    __builtin_amdgcn_s_setprio(1);                                            \
    _Pragma("unroll")                                                         \
    for (int m = 0; m < 4; ++m)                                               \
      _Pragma("unroll")                                                       \
      for (int n = 0; n < 4; ++n)                                             \
        MFMA_BF16_16x16x32(acc[m][n], af[m], bf[n]);                          \
    __builtin_amdgcn_s_setprio(0);                                            \
    SFENCE();                                                                 \
  } while (0)

  float4 pa[4], pb[4];

  // ---- prologue: A(0)->buf0, B(0)->pa->pack->buf0, B(1)->pb in flight ----
  STAGE_A_Z(0, 0);
  LOADB(pa, 0);
  WAIT_VM0();
  PACK_B(pa, sB);
  LOADB(pb, 32);                  // 4 outstanding across the barrier
  WAIT_LGKM0();
  BARRIER();

#pragma unroll 1
  for (int kt2 = 0; kt2 < 128; kt2 += 2) {
    const bool more = (kt2 < 126);
    // ---- even kt = kt2: compute buf0; A(kt+1)->buf1; load pa = B(kt+2) ----
    STAGE_A_Z(1, (kt2 + 1) << 5);
    if (more) LOADB(pa, (kt2 + 2) << 5);
    COMPUTE(0);
    if (more) {
      WAIT_VM6();                 // pb = B(kt2+1) regs ready (2 DMA + 4 pa newer)
      PACK_B(pb, sB + 8192);
      WAIT_VM4();                 // A(kt2+1) DMA done; pa stays in flight
    } else {
      WAIT_VM2();
      PACK_B(pb, sB + 8192);
      WAIT_VM0();
    }
    WAIT_LGKM0();
    BARRIER();
    // ---- odd kt = kt2+1: compute buf1; A(kt+1)->buf0; load pb = B(kt+2) ----
    if (more) {
      STAGE_A_Z(0, (kt2 + 2) << 5);
      LOADB(pb, (kt2 + 3) << 5);
    }
    COMPUTE(1);
    if (more) {
      WAIT_VM6();                 // pa = B(kt2+2) regs ready
      PACK_B(pa, sB);
      WAIT_VM4();
      WAIT_LGKM0();
      BARRIER();
    }
  }

  // C/D layout: col = lane&15, row = (lane>>4)*4 + j
#pragma unroll
  for (int m = 0; m < 4; ++m) {
    const int r0 = aRow0 + wr * 64 + m * 16 + lk * 4;
#pragma unroll
    for (int n = 0; n < 4; ++n) {
      const int col = bCol0 + wc * 64 + n * 16 + lr;
#pragma unroll
      for (int j = 0; j < 4; ++j)
        Ct[(size_t)(r0 + j) * 4096 + col] = f2bf_rne(acc[m][n][j]);
    }
  }
#undef STAGE_A_Z
#undef LOADB
#undef PACK_B
#undef COMPUTE
}

// ---------------------------------------------------------------------------
// out[n, t*512+r] = sum_d z[t,n,d]*dec[t,r,d] + bias. 128x64 tile, BK=32.
// Triple-buffered depth-2 pipeline, counted vmcnt(3). Slot-XOR swizzle
// (source-side for global_load_lds, per-lane constant on frag reads).
// ---------------------------------------------------------------------------
__global__ __launch_bounds__(256, 2) void gemm_out_kernel(
    const u16* __restrict__ Z,    // [8][512][4096]
    const u16* __restrict__ Dec,  // [8][512][4096]
    const float* __restrict__ bias,
    float* __restrict__ out) {    // [512][4096]
  __shared__ char sm[36864];      // 3 bufs x (A 8KB + B 4KB)
  const int lb = blockIdx.x;
  const int swz = ((lb & 7) << 5) | (lb >> 3);  // 256 % 8 == 0
  const int t = swz >> 5;
  const int rem = swz & 31;
  const int nb = rem >> 2, mb = rem & 3;
  const u16* At = Z + ((size_t)t << 21);
  const u16* Bt = Dec + ((size_t)t << 21);
  const int aRow0 = mb << 7, bCol0 = nb << 6;
  const int tid = threadIdx.x;
  const int wv = tid >> 6, ln = tid & 63;
  const int lr = ln & 15, lk = ln >> 4;
  const int wr = wv >> 1, wc = wv & 1;

  fx4 acc[4][2] = {};

  const int kswz = (((tid & 3) ^ ((tid >> 3) & 3)) << 3);
  const u16* Asrc = At + (size_t)(aRow0 + (tid >> 2)) * 4096 + kswz;
  const u16* Bsrc = Bt + (size_t)(bCol0 + (tid >> 2)) * 4096 + kswz;
  const int gr = (lr >> 1) & 3;
  const int aof = (wr * 64 + lr) * 64 + ((lk ^ gr) << 4);          // + m*1024
  const int bof = 8192 + (wc * 32 + lr) * 64 + ((lk ^ gr) << 4);   // + n*1024

#define STAGE_O(buf, kofs)                                                   \
  do {                                                                       \
    _Pragma("unroll")                                                        \
    for (int c = 0; c < 2; ++c)                                              \
      __builtin_amdgcn_global_load_lds(                                      \
          (gvoid*)(Asrc + (size_t)(c << 6) * 4096 + (kofs)),                 \
          (lvoid*)((buf) + c * 4096 + tid * 16), 16, 0, 0);                  \
    __builtin_amdgcn_global_load_lds((gvoid*)(Bsrc + (kofs)),                \
                                     (lvoid*)((buf) + 8192 + tid * 16), 16,  \
                                     0, 0);                                  \
  } while (0)

  char* b0 = sm;
  char* b1 = sm + 12288;
  char* b2 = sm + 24576;
  STAGE_O(b0, 0);
  STAGE_O(b1, 32);
  WAIT_VM3();                     // first stage (3 ops) complete
  BARRIER();

#pragma unroll 1
  for (int kt = 0; kt < 128; ++kt) {
    if (kt + 2 < 128) STAGE_O(b2, (kt + 2) << 5);
    u32x4 af[4], bf[2];
#pragma unroll
    for (int m = 0; m < 4; ++m)
      af[m] = *(const u32x4*)(b0 + aof + m * 1024);
#pragma unroll
    for (int n = 0; n < 2; ++n)
      bf[n] = *(const u32x4*)(b0 + bof + n * 1024);
    WAIT_LGKM0();
    SFENCE();
#pragma unroll
    for (int m = 0; m < 4; ++m)
#pragma unroll
      for (int n = 0; n < 2; ++n)
        MFMA_BF16_16x16x32(acc[m][n], af[m], bf[n]);
    if (kt + 2 < 128) {
      WAIT_VM3();                 // oldest stage (kt+1's buffer) complete
    } else {
      WAIT_VM0();
    }
    BARRIER();
    char* tmp = b0; b0 = b1; b1 = b2; b2 = tmp;
  }

#pragma unroll
  for (int n = 0; n < 2; ++n) {
    const int colg = (t << 9) + bCol0 + wc * 32 + n * 16 + lr;
    const float bv = bias[colg];
#pragma unroll
    for (int m = 0; m < 4; ++m) {
      const int r0 = aRow0 + wr * 64 + m * 16 + lk * 4;
#pragma unroll
      for (int j = 0; j < 4; ++j)
        out[(size_t)(r0 + j) * 4096 + colg] = acc[m][n][j] + bv;
    }
  }
#undef STAGE_O
}

// ---------------------------------------------------------------------------
extern "C" void kernel_launch(void* const* d_in, const int* in_sizes, int n_in,
                              void* d_out, int out_size, void* d_ws, size_t ws_size,
                              hipStream_t stream) {
  const float* x       = (const float*)d_in[0];   // [512][4096]
  const float* cw      = (const float*)d_in[1];   // [16384][4096]
  const int*   indices = (const int*)d_in[2];     // [8][512][4]
  const float* rot     = (const float*)d_in[3];   // [8][4096][4096]
  const float* scales  = (const float*)d_in[4];   // [8]
  const float* bias    = (const float*)d_in[5];   // [4096]
  float* out = (float*)d_out;
  char* ws = (char*)d_ws;

  u16* xb  = (u16*)(ws);                          // 4 MiB
  u16* dec = (u16*)(ws + ((size_t)4 << 20));      // 32 MiB
  u16* z   = (u16*)(ws + ((size_t)36 << 20));     // 32 MiB

  cvtx_kernel<<<dim3(2048), dim3(256), 0, stream>>>(x, xb);
  fused_z_decode_kernel<<<dim3(1280), dim3(256), 0, stream>>>(
      xb, rot, z, cw, indices, scales, dec);
  gemm_out_kernel<<<dim3(256), dim3(256), 0, stream>>>(z, dec, bias, out);
}

// Round 8
// 315.986 us; speedup vs baseline: 1.2302x; 1.1096x over previous
//
#include <hip/hip_runtime.h>

typedef unsigned int uint32;
typedef unsigned short u16;
typedef float fx4 __attribute__((ext_vector_type(4)));
typedef uint32 u32x4 __attribute__((ext_vector_type(4)));
typedef uint32 u32x2 __attribute__((ext_vector_type(2)));

typedef const __attribute__((address_space(1))) void gvoid;
typedef __attribute__((address_space(3))) void lvoid;

#define MFMA_BF16_16x16x32(acc, a, b) \
  asm("v_mfma_f32_16x16x32_bf16 %0, %1, %2, %0" : "+v"(acc) : "v"(a), "v"(b))

#define WAIT_LGKM0() asm volatile("s_waitcnt lgkmcnt(0)" ::: "memory")
#define WAIT_LGKM2() asm volatile("s_waitcnt lgkmcnt(2)" ::: "memory")
#define WAIT_LGKM6() asm volatile("s_waitcnt lgkmcnt(6)" ::: "memory")
#define WAIT_VM0()   asm volatile("s_waitcnt vmcnt(0)" ::: "memory")
#define WAIT_VM3()   asm volatile("s_waitcnt vmcnt(3)" ::: "memory")
#define WAIT_VM4()   asm volatile("s_waitcnt vmcnt(4)" ::: "memory")
#define WAIT_VM8()   asm volatile("s_waitcnt vmcnt(8)" ::: "memory")
#define WAIT_VM12()  asm volatile("s_waitcnt vmcnt(12)" ::: "memory")
#define SFENCE()     __builtin_amdgcn_sched_barrier(0)
#define BARRIER()    do { __builtin_amdgcn_s_barrier(); asm volatile("" ::: "memory"); } while (0)

__device__ __forceinline__ u16 f2bf_rne(float f) {
  uint32 u = __builtin_bit_cast(uint32, f);
  u += 0x7FFFu + ((u >> 16) & 1u);
  return (u16)(u >> 16);
}

__device__ __forceinline__ uint32 cvt_pk_bf16(float lo, float hi) {
  uint32 r;
  asm("v_cvt_pk_bf16_f32 %0, %1, %2" : "=v"(r) : "v"(lo), "v"(hi));
  return r;
}

// ---------------------------------------------------------------------------
// x (fp32) -> bf16
// ---------------------------------------------------------------------------
__global__ __launch_bounds__(256) void cvtx_kernel(const float* __restrict__ x,
                                                   u16* __restrict__ xb) {
  const int i = blockIdx.x * 256 + threadIdx.x;
  float4 v = ((const float4*)x)[i];
  ushort4 o;
  o.x = f2bf_rne(v.x);
  o.y = f2bf_rne(v.y);
  o.z = f2bf_rne(v.z);
  o.w = f2bf_rne(v.w);
  ((ushort4*)xb)[i] = o;
}

// ---------------------------------------------------------------------------
// decode body: dec[t,r,d] = scales[t]*0.25 * sum_k cw[idx[t,r,k], d] (bf16)
// ---------------------------------------------------------------------------
__device__ __forceinline__ void decode_body(
    int bid, const float* __restrict__ cw, const int* __restrict__ indices,
    const float* __restrict__ scales, u16* __restrict__ dec) {
  const int tid = threadIdx.x;
#pragma unroll 1
  for (int rr = 0; rr < 16; ++rr) {
    const int row = bid * 16 + rr;       // t*512 + r
    const int t = row >> 9;
    const int* ip = indices + (size_t)row * 4;
    const float* c0 = cw + (size_t)ip[0] * 4096;
    const float* c1 = cw + (size_t)ip[1] * 4096;
    const float* c2 = cw + (size_t)ip[2] * 4096;
    const float* c3 = cw + (size_t)ip[3] * 4096;
    const float s = scales[t] * 0.25f;
    u16* orow = dec + (size_t)row * 4096;
#pragma unroll
    for (int j = 0; j < 4; ++j) {
      const int d = j * 1024 + tid * 4;
      float4 a = *(const float4*)(c0 + d);
      float4 b = *(const float4*)(c1 + d);
      float4 c = *(const float4*)(c2 + d);
      float4 e = *(const float4*)(c3 + d);
      ushort4 o;
      o.x = f2bf_rne((a.x + b.x + c.x + e.x) * s);
      o.y = f2bf_rne((a.y + b.y + c.y + e.y) * s);
      o.z = f2bf_rne((a.z + b.z + c.z + e.z) * s);
      o.w = f2bf_rne((a.w + b.w + c.w + e.w) * s);
      *(ushort4*)(orow + d) = o;
    }
  }
}

// ---------------------------------------------------------------------------
// Fused: blocks [0,256) decode; blocks [256,1280) z[t] = x_bf16 @ rot[t]^T.
// GEMM: per-t M=512,N=4096,K=4096; 128x128 tile, BK=64, 4 waves.
// Same frame as rounds 5/7 (verified correct, 0 bank conflicts): slot-XOR
// LDS layout, pre-swizzled-source A via global_load_lds, coalesced reg-staged
// B -> cvt_pk_bf16 -> swizzled ds_write; counted vmcnt (12/8), 2 barriers
// per K-tile. NEW (T3/T4-lite): each K-tile split into 4 MFMA phases of 8;
// phase p issues phase p+1's ds_reads + a staging slice, then waits a
// COUNTED lgkmcnt (2/6/2/0, pure-read counts) + sched fence before its
// MFMAs -- ds_read latency and staging issue hide under own-wave MFMA.
// ---------------------------------------------------------------------------
__global__ __launch_bounds__(256, 2) void fused_z_decode_kernel(
    const u16* __restrict__ Xb,    // [512][4096] bf16
    const float* __restrict__ rot, // [8][4096][4096] fp32
    u16* __restrict__ Z,           // [8][512][4096] bf16
    const float* __restrict__ cw, const int* __restrict__ indices,
    const float* __restrict__ scales, u16* __restrict__ dec) {
  __shared__ char sA[32768];      // 2 bufs x 2 subtiles x [128][64B]
  __shared__ char sB[32768];

  const int bid = blockIdx.x;
  if (bid < 256) {
    decode_body(bid, cw, indices, scales, dec);
    return;
  }
  const int lb = bid - 256;
  const int swz = ((lb & 7) << 7) | (lb >> 3);  // XCD-chunked (1024 % 8 == 0)
  const int t = swz >> 7;
  const int rem = swz & 127;
  const int nb = rem >> 2, mb = rem & 3;        // mb-sharers of B-panel adjacent
  const float* Bt = rot + ((size_t)t << 24);
  u16* Ct = Z + ((size_t)t << 21);
  const int aRow0 = mb << 7, bCol0 = nb << 7;
  const int tid = threadIdx.x;
  const int wv = tid >> 6, ln = tid & 63;
  const int lr = ln & 15, lk = ln >> 4;
  const int wr = wv >> 1, wc = wv & 1;

  fx4 acc[4][4] = {};

  // ---- A staging: source pre-swizzle (16B chunk permute within 64B row)
  const u16* Asrc = Xb + (size_t)(aRow0 + (ln >> 2)) * 4096 +
                    (((ln & 3) ^ ((ln >> 3) & 3)) << 3);
  // ---- B staging (reg, coalesced): rows R0+8j, float4 chunk cB = ln&7
  const int R0 = wv * 32 + (ln >> 3);
  const int cB = ln & 7;
  const float* Bsrc = Bt + (size_t)(bCol0 + R0) * 4096 + cB * 4;
  // swizzled LDS write base within a q-subtile (j-independent: rows step by 8)
  const int bwr = R0 * 64 + ((((cB >> 1) ^ ((R0 >> 1) & 3)) << 4)) + ((cB & 1) << 3);
  // ---- frag read offsets: slot-XOR folded into per-lane constant
  const int gr = (lr >> 1) & 3;
  const int aof = (wr * 64 + lr) * 64 + ((lk ^ gr) << 4);  // + q*8192 + m*1024
  const int bof = (wc * 64 + lr) * 64 + ((lk ^ gr) << 4);  // + q*8192 + n*1024

#define STAGE_A_Z(dbuf, kofs)                                                 \
  _Pragma("unroll")                                                           \
  for (int c = 0; c < 4; ++c)                                                 \
    __builtin_amdgcn_global_load_lds(                                         \
        (gvoid*)(Asrc + (size_t)(((c & 1) * 4 + wv) << 4) * 4096 +            \
                 ((c >> 1) << 5) + (kofs)),                                   \
        (lvoid*)(sA + (dbuf) * 16384 + c * 4096 + tid * 16), 16, 0, 0)

#define LOADB4(p, kofs, Q)                                                    \
  do {                                                                        \
    const float* bp_ = Bsrc + (kofs) + (Q) * 32;                              \
    p[(Q) * 4 + 0] = *(const float4*)(bp_);                                   \
    p[(Q) * 4 + 1] = *(const float4*)(bp_ + 8 * 4096);                        \
    p[(Q) * 4 + 2] = *(const float4*)(bp_ + 16 * 4096);                       \
    p[(Q) * 4 + 3] = *(const float4*)(bp_ + 24 * 4096);                       \
  } while (0)

#define PACK_B(p, dst)                                                        \
  do {                                                                        \
    u32x2 w_;                                                                 \
    w_[0] = cvt_pk_bf16(p[0].x, p[0].y); w_[1] = cvt_pk_bf16(p[0].z, p[0].w); \
    *(u32x2*)((dst) + bwr) = w_;                                              \
    w_[0] = cvt_pk_bf16(p[1].x, p[1].y); w_[1] = cvt_pk_bf16(p[1].z, p[1].w); \
    *(u32x2*)((dst) + bwr + 512) = w_;                                        \
    w_[0] = cvt_pk_bf16(p[2].x, p[2].y); w_[1] = cvt_pk_bf16(p[2].z, p[2].w); \
    *(u32x2*)((dst) + bwr + 1024) = w_;                                       \
    w_[0] = cvt_pk_bf16(p[3].x, p[3].y); w_[1] = cvt_pk_bf16(p[3].z, p[3].w); \
    *(u32x2*)((dst) + bwr + 1536) = w_;                                       \
    w_[0] = cvt_pk_bf16(p[4].x, p[4].y); w_[1] = cvt_pk_bf16(p[4].z, p[4].w); \
    *(u32x2*)((dst) + 8192 + bwr) = w_;                                       \
    w_[0] = cvt_pk_bf16(p[5].x, p[5].y); w_[1] = cvt_pk_bf16(p[5].z, p[5].w); \
    *(u32x2*)((dst) + 8192 + bwr + 512) = w_;                                 \
    w_[0] = cvt_pk_bf16(p[6].x, p[6].y); w_[1] = cvt_pk_bf16(p[6].z, p[6].w); \
    *(u32x2*)((dst) + 8192 + bwr + 1024) = w_;                                \
    w_[0] = cvt_pk_bf16(p[7].x, p[7].y); w_[1] = cvt_pk_bf16(p[7].z, p[7].w); \
    *(u32x2*)((dst) + 8192 + bwr + 1536) = w_;                                \
  } while (0)

#define PH_READS0(d)                                                          \
  do {                                                                        \
    const char* pA_ = sA + (d) * 16384;                                       \
    const char* pB_ = sB + (d) * 16384;                                       \
    af0[0] = *(const u32x4*)(pA_ + aof);                                      \
    af0[1] = *(const u32x4*)(pA_ + aof + 1024);                               \
    af0[2] = *(const u32x4*)(pA_ + aof + 2048);                               \
    af0[3] = *(const u32x4*)(pA_ + aof + 3072);                               \
    bf0[0] = *(const u32x4*)(pB_ + bof);                                      \
    bf0[1] = *(const u32x4*)(pB_ + bof + 1024);                               \
  } while (0)
#define PH_READS1(d)                                                          \
  do {                                                                        \
    const char* pB_ = sB + (d) * 16384;                                       \
    bf0[2] = *(const u32x4*)(pB_ + bof + 2048);                               \
    bf0[3] = *(const u32x4*)(pB_ + bof + 3072);                               \
  } while (0)
#define PH_READS2(d)                                                          \
  do {                                                                        \
    const char* pA_ = sA + (d) * 16384 + 8192;                                \
    const char* pB_ = sB + (d) * 16384 + 8192;                                \
    af1[0] = *(const u32x4*)(pA_ + aof);                                      \
    af1[1] = *(const u32x4*)(pA_ + aof + 1024);                               \
    af1[2] = *(const u32x4*)(pA_ + aof + 2048);                               \
    af1[3] = *(const u32x4*)(pA_ + aof + 3072);                               \
    bf1[0] = *(const u32x4*)(pB_ + bof);                                      \
    bf1[1] = *(const u32x4*)(pB_ + bof + 1024);                               \
  } while (0)
#define PH_READS3(d)                                                          \
  do {                                                                        \
    const char* pB_ = sB + (d) * 16384 + 8192;                                \
    bf1[2] = *(const u32x4*)(pB_ + bof + 2048);                               \
    bf1[3] = *(const u32x4*)(pB_ + bof + 3072);                               \
  } while (0)

#define MFMA_PH(AF, BF, NA, NB)                                               \
  do {                                                                        \
    __builtin_amdgcn_s_setprio(1);                                            \
    _Pragma("unroll")                                                         \
    for (int m = 0; m < 4; ++m) {                                             \
      MFMA_BF16_16x16x32(acc[m][NA], AF[m], BF[NA]);                          \
      MFMA_BF16_16x16x32(acc[m][NB], AF[m], BF[NB]);                          \
    }                                                                         \
    __builtin_amdgcn_s_setprio(0);                                            \
  } while (0)

  u32x4 af0[4], af1[4], bf0[4], bf1[4];
  float4 pa[8], pb[8];

  // ---- prologue: A(0)->buf0; B(0)->pa->pack->buf0; B(1)->pb in flight ----
  STAGE_A_Z(0, 0);
  LOADB4(pa, 0, 0);
  LOADB4(pa, 0, 1);
  WAIT_VM0();
  PACK_B(pa, sB);
  LOADB4(pb, 64, 0);
  LOADB4(pb, 64, 1);              // 8 outstanding across the barrier
  WAIT_LGKM0();
  BARRIER();

#pragma unroll 1
  for (int kt2 = 0; kt2 < 62; kt2 += 2) {
    // ---- even kt: compute buf0; stage A(kt+1)->buf1; load pa=B(kt+2);
    //      pack pb=B(kt+1)->buf1 ----
    PH_READS0(0);
    STAGE_A_Z(1, (kt2 + 1) << 6);
    PH_READS1(0);
    WAIT_LGKM2();
    SFENCE();
    MFMA_PH(af0, bf0, 0, 1);
    LOADB4(pa, (kt2 + 2) << 6, 0);
    PH_READS2(0);
    WAIT_LGKM6();
    SFENCE();
    MFMA_PH(af0, bf0, 2, 3);
    LOADB4(pa, (kt2 + 2) << 6, 1);
    PH_READS3(0);
    WAIT_LGKM2();
    SFENCE();
    MFMA_PH(af1, bf1, 0, 1);
    WAIT_LGKM0();
    SFENCE();
    MFMA_PH(af1, bf1, 2, 3);
    WAIT_VM12();                  // pb arrived (A:4 + pa:8 newer in flight)
    PACK_B(pb, sB + 16384);
    WAIT_VM8();                   // A DMA done; pa stays in flight
    WAIT_LGKM0();
    BARRIER();
    // ---- odd kt: compute buf1; stage A(kt+1)->buf0; load pb=B(kt+2);
    //      pack pa->buf0 ----
    PH_READS0(1);
    STAGE_A_Z(0, (kt2 + 2) << 6);
    PH_READS1(1);
    WAIT_LGKM2();
    SFENCE();
    MFMA_PH(af0, bf0, 0, 1);
    LOADB4(pb, (kt2 + 3) << 6, 0);
    PH_READS2(1);
    WAIT_LGKM6();
    SFENCE();
    MFMA_PH(af0, bf0, 2, 3);
    LOADB4(pb, (kt2 + 3) << 6, 1);
    PH_READS3(1);
    WAIT_LGKM2();
    SFENCE();
    MFMA_PH(af1, bf1, 0, 1);
    WAIT_LGKM0();
    SFENCE();
    MFMA_PH(af1, bf1, 2, 3);
    WAIT_VM12();                  // pa arrived
    PACK_B(pa, sB);
    WAIT_VM8();
    WAIT_LGKM0();
    BARRIER();
  }
  // ---- kt = 62 (even, last staged step): stage A(63); pack pb=B(63) ----
  {
    PH_READS0(0);
    STAGE_A_Z(1, 63 << 6);
    PH_READS1(0);
    WAIT_LGKM2();
    SFENCE();
    MFMA_PH(af0, bf0, 0, 1);
    PH_READS2(0);
    WAIT_LGKM6();
    SFENCE();
    MFMA_PH(af0, bf0, 2, 3);
    PH_READS3(0);
    WAIT_LGKM2();
    SFENCE();
    MFMA_PH(af1, bf1, 0, 1);
    WAIT_LGKM0();
    SFENCE();
    MFMA_PH(af1, bf1, 2, 3);
    WAIT_VM4();                   // pb done (A:4 may remain)
    PACK_B(pb, sB + 16384);
    WAIT_VM0();                   // A done
    WAIT_LGKM0();
    BARRIER();
  }
  // ---- kt = 63 (last): compute buf1 only ----
  {
    PH_READS0(1);
    PH_READS1(1);
    WAIT_LGKM2();
    SFENCE();
    MFMA_PH(af0, bf0, 0, 1);
    PH_READS2(1);
    WAIT_LGKM6();
    SFENCE();
    MFMA_PH(af0, bf0, 2, 3);
    PH_READS3(1);
    WAIT_LGKM2();
    SFENCE();
    MFMA_PH(af1, bf1, 0, 1);
    WAIT_LGKM0();
    SFENCE();
    MFMA_PH(af1, bf1, 2, 3);
  }

  // C/D layout: col = lane&15, row = (lane>>4)*4 + j
#pragma unroll
  for (int m = 0; m < 4; ++m) {
    const int r0 = aRow0 + wr * 64 + m * 16 + lk * 4;
#pragma unroll
    for (int n = 0; n < 4; ++n) {
      const int col = bCol0 + wc * 64 + n * 16 + lr;
#pragma unroll
      for (int j = 0; j < 4; ++j)
        Ct[(size_t)(r0 + j) * 4096 + col] = f2bf_rne(acc[m][n][j]);
    }
  }
#undef STAGE_A_Z
#undef LOADB4
#undef PACK_B
#undef PH_READS0
#undef PH_READS1
#undef PH_READS2
#undef PH_READS3
#undef MFMA_PH
}

// ---------------------------------------------------------------------------
// out[n, t*512+r] = sum_d z[t,n,d]*dec[t,r,d] + bias. 128x64 tile, BK=32.
// Triple-buffered depth-2 pipeline, counted vmcnt(3). Slot-XOR swizzle
// (source-side for global_load_lds, per-lane constant on frag reads).
// ---------------------------------------------------------------------------
__global__ __launch_bounds__(256, 2) void gemm_out_kernel(
    const u16* __restrict__ Z,    // [8][512][4096]
    const u16* __restrict__ Dec,  // [8][512][4096]
    const float* __restrict__ bias,
    float* __restrict__ out) {    // [512][4096]
  __shared__ char sm[36864];      // 3 bufs x (A 8KB + B 4KB)
  const int lb = blockIdx.x;
  const int swz = ((lb & 7) << 5) | (lb >> 3);  // 256 % 8 == 0
  const int t = swz >> 5;
  const int rem = swz & 31;
  const int nb = rem >> 2, mb = rem & 3;
  const u16* At = Z + ((size_t)t << 21);
  const u16* Bt = Dec + ((size_t)t << 21);
  const int aRow0 = mb << 7, bCol0 = nb << 6;
  const int tid = threadIdx.x;
  const int wv = tid >> 6, ln = tid & 63;
  const int lr = ln & 15, lk = ln >> 4;
  const int wr = wv >> 1, wc = wv & 1;

  fx4 acc[4][2] = {};

  const int kswz = (((tid & 3) ^ ((tid >> 3) & 3)) << 3);
  const u16* Asrc = At + (size_t)(aRow0 + (tid >> 2)) * 4096 + kswz;
  const u16* Bsrc = Bt + (size_t)(bCol0 + (tid >> 2)) * 4096 + kswz;
  const int gr = (lr >> 1) & 3;
  const int aof = (wr * 64 + lr) * 64 + ((lk ^ gr) << 4);          // + m*1024
  const int bof = 8192 + (wc * 32 + lr) * 64 + ((lk ^ gr) << 4);   // + n*1024

#define STAGE_O(buf, kofs)                                                   \
  do {                                                                       \
    _Pragma("unroll")                                                        \
    for (int c = 0; c < 2; ++c)                                              \
      __builtin_amdgcn_global_load_lds(                                      \
          (gvoid*)(Asrc + (size_t)(c << 6) * 4096 + (kofs)),                 \
          (lvoid*)((buf) + c * 4096 + tid * 16), 16, 0, 0);                  \
    __builtin_amdgcn_global_load_lds((gvoid*)(Bsrc + (kofs)),                \
                                     (lvoid*)((buf) + 8192 + tid * 16), 16,  \
                                     0, 0);                                  \
  } while (0)

  char* b0 = sm;
  char* b1 = sm + 12288;
  char* b2 = sm + 24576;
  STAGE_O(b0, 0);
  STAGE_O(b1, 32);
  WAIT_VM3();                     // first stage (3 ops) complete
  BARRIER();

#pragma unroll 1
  for (int kt = 0; kt < 128; ++kt) {
    if (kt + 2 < 128) STAGE_O(b2, (kt + 2) << 5);
    u32x4 af[4], bf[2];
#pragma unroll
    for (int m = 0; m < 4; ++m)
      af[m] = *(const u32x4*)(b0 + aof + m * 1024);
#pragma unroll
    for (int n = 0; n < 2; ++n)
      bf[n] = *(const u32x4*)(b0 + bof + n * 1024);
    WAIT_LGKM0();
    SFENCE();
#pragma unroll
    for (int m = 0; m < 4; ++m)
#pragma unroll
      for (int n = 0; n < 2; ++n)
        MFMA_BF16_16x16x32(acc[m][n], af[m], bf[n]);
    if (kt + 2 < 128) {
      WAIT_VM3();                 // oldest stage (kt+1's buffer) complete
    } else {
      WAIT_VM0();
    }
    BARRIER();
    char* tmp = b0; b0 = b1; b1 = b2; b2 = tmp;
  }

#pragma unroll
  for (int n = 0; n < 2; ++n) {
    const int colg = (t << 9) + bCol0 + wc * 32 + n * 16 + lr;
    const float bv = bias[colg];
#pragma unroll
    for (int m = 0; m < 4; ++m) {
      const int r0 = aRow0 + wr * 64 + m * 16 + lk * 4;
#pragma unroll
      for (int j = 0; j < 4; ++j)
        out[(size_t)(r0 + j) * 4096 + colg] = acc[m][n][j] + bv;
    }
  }
#undef STAGE_O
}

// ---------------------------------------------------------------------------
extern "C" void kernel_launch(void* const* d_in, const int* in_sizes, int n_in,
                              void* d_out, int out_size, void* d_ws, size_t ws_size,
                              hipStream_t stream) {
  const float* x       = (const float*)d_in[0];   // [512][4096]
  const float* cw      = (const float*)d_in[1];   // [16384][4096]
  const int*   indices = (const int*)d_in[2];     // [8][512][4]
  const float* rot     = (const float*)d_in[3];   // [8][4096][4096]
  const float* scales  = (const float*)d_in[4];   // [8]
  const float* bias    = (const float*)d_in[5];   // [4096]
  float* out = (float*)d_out;
  char* ws = (char*)d_ws;

  u16* xb  = (u16*)(ws);                          // 4 MiB
  u16* dec = (u16*)(ws + ((size_t)4 << 20));      // 32 MiB
  u16* z   = (u16*)(ws + ((size_t)36 << 20));     // 32 MiB

  cvtx_kernel<<<dim3(2048), dim3(256), 0, stream>>>(x, xb);
  fused_z_decode_kernel<<<dim3(1280), dim3(256), 0, stream>>>(
      xb, rot, z, cw, indices, scales, dec);
  gemm_out_kernel<<<dim3(256), dim3(256), 0, stream>>>(z, dec, bias, out);
}

// Round 10
// 298.468 us; speedup vs baseline: 1.3024x; 1.0587x over previous
//
#include <hip/hip_runtime.h>

typedef unsigned int uint32;
typedef unsigned short u16;
typedef float fx4 __attribute__((ext_vector_type(4)));
typedef uint32 u32x4 __attribute__((ext_vector_type(4)));
typedef uint32 u32x2 __attribute__((ext_vector_type(2)));

typedef const __attribute__((address_space(1))) void gvoid;
typedef __attribute__((address_space(3))) void lvoid;

#define MFMA_BF16_16x16x32(acc, a, b) \
  asm("v_mfma_f32_16x16x32_bf16 %0, %1, %2, %0" : "+v"(acc) : "v"(a), "v"(b))

#define WAIT_LGKM0() asm volatile("s_waitcnt lgkmcnt(0)" ::: "memory")
#define WAIT_LGKM2() asm volatile("s_waitcnt lgkmcnt(2)" ::: "memory")
#define WAIT_LGKM6() asm volatile("s_waitcnt lgkmcnt(6)" ::: "memory")
#define WAIT_VM0()   asm volatile("s_waitcnt vmcnt(0)" ::: "memory")
#define WAIT_VM3()   asm volatile("s_waitcnt vmcnt(3)" ::: "memory")
#define WAIT_VM6()   asm volatile("s_waitcnt vmcnt(6)" ::: "memory")
#define WAIT_VM8()   asm volatile("s_waitcnt vmcnt(8)" ::: "memory")
#define WAIT_VM16()  asm volatile("s_waitcnt vmcnt(16)" ::: "memory")
#define SFENCE()     __builtin_amdgcn_sched_barrier(0)
#define BARRIER()    do { __builtin_amdgcn_s_barrier(); asm volatile("" ::: "memory"); } while (0)

__device__ __forceinline__ u16 f2bf_rne(float f) {
  uint32 u = __builtin_bit_cast(uint32, f);
  u += 0x7FFFu + ((u >> 16) & 1u);
  return (u16)(u >> 16);
}

__device__ __forceinline__ uint32 cvt_pk_bf16(float lo, float hi) {
  uint32 r;
  asm("v_cvt_pk_bf16_f32 %0, %1, %2" : "=v"(r) : "v"(lo), "v"(hi));
  return r;
}

// ---------------------------------------------------------------------------
// x (fp32) -> bf16
// ---------------------------------------------------------------------------
__global__ __launch_bounds__(256) void cvtx_kernel(const float* __restrict__ x,
                                                   u16* __restrict__ xb) {
  const int i = blockIdx.x * 256 + threadIdx.x;
  float4 v = ((const float4*)x)[i];
  ushort4 o;
  o.x = f2bf_rne(v.x);
  o.y = f2bf_rne(v.y);
  o.z = f2bf_rne(v.z);
  o.w = f2bf_rne(v.w);
  ((ushort4*)xb)[i] = o;
}

// ---------------------------------------------------------------------------
// decode body: dec[t,r,d] = scales[t]*0.25 * sum_k cw[idx[t,r,k], d] (bf16)
// ---------------------------------------------------------------------------
__device__ __forceinline__ void decode_body(
    int bid, const float* __restrict__ cw, const int* __restrict__ indices,
    const float* __restrict__ scales, u16* __restrict__ dec) {
  const int tid = threadIdx.x;
#pragma unroll 1
  for (int rr = 0; rr < 16; ++rr) {
    const int row = bid * 16 + rr;       // t*512 + r
    const int t = row >> 9;
    const int* ip = indices + (size_t)row * 4;
    const float* c0 = cw + (size_t)ip[0] * 4096;
    const float* c1 = cw + (size_t)ip[1] * 4096;
    const float* c2 = cw + (size_t)ip[2] * 4096;
    const float* c3 = cw + (size_t)ip[3] * 4096;
    const float s = scales[t] * 0.25f;
    u16* orow = dec + (size_t)row * 4096;
#pragma unroll
    for (int j = 0; j < 4; ++j) {
      const int d = j * 1024 + tid * 4;
      float4 a = *(const float4*)(c0 + d);
      float4 b = *(const float4*)(c1 + d);
      float4 c = *(const float4*)(c2 + d);
      float4 e = *(const float4*)(c3 + d);
      ushort4 o;
      o.x = f2bf_rne((a.x + b.x + c.x + e.x) * s);
      o.y = f2bf_rne((a.y + b.y + c.y + e.y) * s);
      o.z = f2bf_rne((a.z + b.z + c.z + e.z) * s);
      o.w = f2bf_rne((a.w + b.w + c.w + e.w) * s);
      *(ushort4*)(orow + d) = o;
    }
  }
}

// ---------------------------------------------------------------------------
// Fused: blocks [0,256) decode; blocks [256,1280) z[t] = x_bf16 @ rot[t]^T.
// GEMM: per-t M=512,N=4096,K=4096; 128x128 tile, BK=64, 4 waves. Round-8
// frame (slot-XOR LDS, pre-swizzled-source A DMA, coalesced reg-staged B,
// 4-phase counted-lgkm MFMA interleave, 1 barrier per K-step). Changes:
// (a) EVERY issue group pinned with sched_barrier(0) so counted-wait
//     semantics are order-GUARANTEED, not scheduler-dependent (round-9
//     failure root cause);
// (b) depth-3 B pipeline with TAIL-pack and 3 register sets (pb,pc,pa):
//     step kt packs B(kt+1) (retired 2 steps ago -> NO wait before pack),
//     reloads same set with B(kt+4); single steady tail wait vmcnt(8)
//     retires B(kt+3)+A(kt+1), each with >= 1 full step of latency cover.
// ---------------------------------------------------------------------------
__global__ __launch_bounds__(256, 2) void fused_z_decode_kernel(
    const u16* __restrict__ Xb,    // [512][4096] bf16
    const float* __restrict__ rot, // [8][4096][4096] fp32
    u16* __restrict__ Z,           // [8][512][4096] bf16
    const float* __restrict__ cw, const int* __restrict__ indices,
    const float* __restrict__ scales, u16* __restrict__ dec) {
  __shared__ char sA[32768];      // 2 bufs x 2 subtiles x [128][64B]
  __shared__ char sB[32768];

  const int bid = blockIdx.x;
  if (bid < 256) {
    decode_body(bid, cw, indices, scales, dec);
    return;
  }
  const int lb = bid - 256;
  const int swz = ((lb & 7) << 7) | (lb >> 3);  // XCD-chunked (1024 % 8 == 0)
  const int t = swz >> 7;
  const int rem = swz & 127;
  const int nb = rem >> 2, mb = rem & 3;        // mb-sharers of B-panel adjacent
  const float* Bt = rot + ((size_t)t << 24);
  u16* Ct = Z + ((size_t)t << 21);
  const int aRow0 = mb << 7, bCol0 = nb << 7;
  const int tid = threadIdx.x;
  const int wv = tid >> 6, ln = tid & 63;
  const int lr = ln & 15, lk = ln >> 4;
  const int wr = wv >> 1, wc = wv & 1;

  fx4 acc[4][4] = {};

  // ---- A staging: source pre-swizzle (16B chunk permute within 64B row)
  const u16* Asrc = Xb + (size_t)(aRow0 + (ln >> 2)) * 4096 +
                    (((ln & 3) ^ ((ln >> 3) & 3)) << 3);
  // ---- B staging (reg, coalesced): rows R0+8j, float4 chunk cB = ln&7
  const int R0 = wv * 32 + (ln >> 3);
  const int cB = ln & 7;
  const float* Bsrc = Bt + (size_t)(bCol0 + R0) * 4096 + cB * 4;
  // swizzled LDS write base within a q-subtile (j-independent: rows step by 8)
  const int bwr = R0 * 64 + ((((cB >> 1) ^ ((R0 >> 1) & 3)) << 4)) + ((cB & 1) << 3);
  // ---- frag read offsets: slot-XOR folded into per-lane constant
  const int gr = (lr >> 1) & 3;
  const int aof = (wr * 64 + lr) * 64 + ((lk ^ gr) << 4);  // + q*8192 + m*1024
  const int bof = (wc * 64 + lr) * 64 + ((lk ^ gr) << 4);  // + q*8192 + n*1024

#define STAGE_A_Z(dbuf, kofs)                                                 \
  _Pragma("unroll")                                                           \
  for (int c = 0; c < 4; ++c)                                                 \
    __builtin_amdgcn_global_load_lds(                                         \
        (gvoid*)(Asrc + (size_t)(((c & 1) * 4 + wv) << 4) * 4096 +            \
                 ((c >> 1) << 5) + (kofs)),                                   \
        (lvoid*)(sA + (dbuf) * 16384 + c * 4096 + tid * 16), 16, 0, 0)

#define LOADB4(p, kofs, Q)                                                    \
  do {                                                                        \
    const float* bp_ = Bsrc + (kofs) + (Q) * 32;                              \
    p[(Q) * 4 + 0] = *(const float4*)(bp_);                                   \
    p[(Q) * 4 + 1] = *(const float4*)(bp_ + 8 * 4096);                        \
    p[(Q) * 4 + 2] = *(const float4*)(bp_ + 16 * 4096);                       \
    p[(Q) * 4 + 3] = *(const float4*)(bp_ + 24 * 4096);                       \
  } while (0)

#define PACK_B(p, dst)                                                        \
  do {                                                                        \
    u32x2 w_;                                                                 \
    w_[0] = cvt_pk_bf16(p[0].x, p[0].y); w_[1] = cvt_pk_bf16(p[0].z, p[0].w); \
    *(u32x2*)((dst) + bwr) = w_;                                              \
    w_[0] = cvt_pk_bf16(p[1].x, p[1].y); w_[1] = cvt_pk_bf16(p[1].z, p[1].w); \
    *(u32x2*)((dst) + bwr + 512) = w_;                                        \
    w_[0] = cvt_pk_bf16(p[2].x, p[2].y); w_[1] = cvt_pk_bf16(p[2].z, p[2].w); \
    *(u32x2*)((dst) + bwr + 1024) = w_;                                       \
    w_[0] = cvt_pk_bf16(p[3].x, p[3].y); w_[1] = cvt_pk_bf16(p[3].z, p[3].w); \
    *(u32x2*)((dst) + bwr + 1536) = w_;                                       \
    w_[0] = cvt_pk_bf16(p[4].x, p[4].y); w_[1] = cvt_pk_bf16(p[4].z, p[4].w); \
    *(u32x2*)((dst) + 8192 + bwr) = w_;                                       \
    w_[0] = cvt_pk_bf16(p[5].x, p[5].y); w_[1] = cvt_pk_bf16(p[5].z, p[5].w); \
    *(u32x2*)((dst) + 8192 + bwr + 512) = w_;                                 \
    w_[0] = cvt_pk_bf16(p[6].x, p[6].y); w_[1] = cvt_pk_bf16(p[6].z, p[6].w); \
    *(u32x2*)((dst) + 8192 + bwr + 1024) = w_;                                \
    w_[0] = cvt_pk_bf16(p[7].x, p[7].y); w_[1] = cvt_pk_bf16(p[7].z, p[7].w); \
    *(u32x2*)((dst) + 8192 + bwr + 1536) = w_;                                \
  } while (0)

#define PH_READS0(d)                                                          \
  do {                                                                        \
    const char* pA_ = sA + (d) * 16384;                                       \
    const char* pB_ = sB + (d) * 16384;                                       \
    af0[0] = *(const u32x4*)(pA_ + aof);                                      \
    af0[1] = *(const u32x4*)(pA_ + aof + 1024);                               \
    af0[2] = *(const u32x4*)(pA_ + aof + 2048);                               \
    af0[3] = *(const u32x4*)(pA_ + aof + 3072);                               \
    bf0[0] = *(const u32x4*)(pB_ + bof);                                      \
    bf0[1] = *(const u32x4*)(pB_ + bof + 1024);                               \
  } while (0)
#define PH_READS1(d)                                                          \
  do {                                                                        \
    const char* pB_ = sB + (d) * 16384;                                       \
    bf0[2] = *(const u32x4*)(pB_ + bof + 2048);                               \
    bf0[3] = *(const u32x4*)(pB_ + bof + 3072);                               \
  } while (0)
#define PH_READS2(d)                                                          \
  do {                                                                        \
    const char* pA_ = sA + (d) * 16384 + 8192;                                \
    const char* pB_ = sB + (d) * 16384 + 8192;                                \
    af1[0] = *(const u32x4*)(pA_ + aof);                                      \
    af1[1] = *(const u32x4*)(pA_ + aof + 1024);                               \
    af1[2] = *(const u32x4*)(pA_ + aof + 2048);                               \
    af1[3] = *(const u32x4*)(pA_ + aof + 3072);                               \
    bf1[0] = *(const u32x4*)(pB_ + bof);                                      \
    bf1[1] = *(const u32x4*)(pB_ + bof + 1024);                               \
  } while (0)
#define PH_READS3(d)                                                          \
  do {                                                                        \
    const char* pB_ = sB + (d) * 16384 + 8192;                                \
    bf1[2] = *(const u32x4*)(pB_ + bof + 2048);                               \
    bf1[3] = *(const u32x4*)(pB_ + bof + 3072);                               \
  } while (0)

#define MFMA_PH(AF, BF, NA, NB)                                               \
  do {                                                                        \
    __builtin_amdgcn_s_setprio(1);                                            \
    _Pragma("unroll")                                                         \
    for (int m = 0; m < 4; ++m) {                                             \
      MFMA_BF16_16x16x32(acc[m][NA], AF[m], BF[NA]);                          \
      MFMA_BF16_16x16x32(acc[m][NB], AF[m], BF[NB]);                          \
    }                                                                         \
    __builtin_amdgcn_s_setprio(0);                                            \
  } while (0)

// One K-step. d = buffer computed; SET holds B(kt+1) (pack operand, retired
// 2 steps ago), reloaded with B(kt+4) at the tail. All issue groups fenced.
#define STEP_Z(d, SET, kt, DOLOAD, DOSTAGE, TAILW)                            \
  do {                                                                        \
    PH_READS0(d);                                                             \
    SFENCE();                                                                 \
    if (DOSTAGE) { STAGE_A_Z((d) ^ 1, ((kt) + 1) << 6); }                     \
    SFENCE();                                                                 \
    PH_READS1(d);                                                             \
    SFENCE();                                                                 \
    WAIT_LGKM2();                                                             \
    SFENCE();                                                                 \
    MFMA_PH(af0, bf0, 0, 1);                                                  \
    PH_READS2(d);                                                             \
    SFENCE();                                                                 \
    WAIT_LGKM6();                                                             \
    SFENCE();                                                                 \
    MFMA_PH(af0, bf0, 2, 3);                                                  \
    PH_READS3(d);                                                             \
    SFENCE();                                                                 \
    WAIT_LGKM2();                                                             \
    SFENCE();                                                                 \
    MFMA_PH(af1, bf1, 0, 1);                                                  \
    WAIT_LGKM0();                                                             \
    SFENCE();                                                                 \
    MFMA_PH(af1, bf1, 2, 3);                                                  \
    PACK_B(SET, sB + ((d) ^ 1) * 16384);                                      \
    SFENCE();                                                                 \
    if (DOLOAD) { LOADB4(SET, ((kt) + 4) << 6, 0);                            \
                  LOADB4(SET, ((kt) + 4) << 6, 1); }                          \
    SFENCE();                                                                 \
    TAILW;                                                                    \
    WAIT_LGKM0();                                                             \
    BARRIER();                                                                \
  } while (0)

  u32x4 af0[4], af1[4], bf0[4], bf1[4];
  float4 pa[8], pb[8], pc[8];

  // ---- prologue: A(0)->buf0; B(0)->pa->pack->buf0; pb=B(1), pc=B(2),
  //      pa=B(3) issued; VM16 -> B(1) retired, B(2)/B(3) in flight ----
  STAGE_A_Z(0, 0);
  SFENCE();
  LOADB4(pa, 0, 0);
  LOADB4(pa, 0, 1);
  SFENCE();
  WAIT_VM0();
  SFENCE();
  PACK_B(pa, sB);
  SFENCE();
  LOADB4(pb, 1 << 6, 0);
  LOADB4(pb, 1 << 6, 1);
  SFENCE();
  LOADB4(pc, 2 << 6, 0);
  LOADB4(pc, 2 << 6, 1);
  SFENCE();
  LOADB4(pa, 3 << 6, 0);
  LOADB4(pa, 3 << 6, 1);
  SFENCE();
  WAIT_VM16();
  WAIT_LGKM0();
  BARRIER();

  // steady: steps 0..59 (6-step groups: set period 3 x buffer period 2)
#pragma unroll 1
  for (int kt6 = 0; kt6 < 60; kt6 += 6) {
    STEP_Z(0, pb, kt6 + 0, true, true, WAIT_VM8());
    STEP_Z(1, pc, kt6 + 1, true, true, WAIT_VM8());
    STEP_Z(0, pa, kt6 + 2, true, true, WAIT_VM8());
    STEP_Z(1, pb, kt6 + 3, true, true, WAIT_VM8());
    STEP_Z(0, pc, kt6 + 4, true, true, WAIT_VM8());
    STEP_Z(1, pa, kt6 + 5, true, true, WAIT_VM8());
  }
  // epilogue: steps 60..62 (no loads; VM0 tails keep A guarantees exact)
  STEP_Z(0, pb, 60, false, true, WAIT_VM0());
  STEP_Z(1, pc, 61, false, true, WAIT_VM0());
  STEP_Z(0, pa, 62, false, true, WAIT_VM0());
  // step 63: compute buf1 only
  {
    PH_READS0(1);
    SFENCE();
    PH_READS1(1);
    SFENCE();
    WAIT_LGKM2();
    SFENCE();
    MFMA_PH(af0, bf0, 0, 1);
    PH_READS2(1);
    SFENCE();
    WAIT_LGKM6();
    SFENCE();
    MFMA_PH(af0, bf0, 2, 3);
    PH_READS3(1);
    SFENCE();
    WAIT_LGKM2();
    SFENCE();
    MFMA_PH(af1, bf1, 0, 1);
    WAIT_LGKM0();
    SFENCE();
    MFMA_PH(af1, bf1, 2, 3);
  }

  // C/D layout: col = lane&15, row = (lane>>4)*4 + j
#pragma unroll
  for (int m = 0; m < 4; ++m) {
    const int r0 = aRow0 + wr * 64 + m * 16 + lk * 4;
#pragma unroll
    for (int n = 0; n < 4; ++n) {
      const int col = bCol0 + wc * 64 + n * 16 + lr;
#pragma unroll
      for (int j = 0; j < 4; ++j)
        Ct[(size_t)(r0 + j) * 4096 + col] = f2bf_rne(acc[m][n][j]);
    }
  }
#undef STAGE_A_Z
#undef LOADB4
#undef PACK_B
#undef PH_READS0
#undef PH_READS1
#undef PH_READS2
#undef PH_READS3
#undef MFMA_PH
#undef STEP_Z
}

// ---------------------------------------------------------------------------
// out[n, t*512+r] = sum_d z[t,n,d]*dec[t,r,d] + bias. 128x64 tile, BK=32.
// QUAD-buffered depth-3 pipeline (grid = 256 = 1 block/CU: no cross-block
// cover, so ~2 full steps hide the ~900cyc HBM latency). Counted vmcnt(6)
// steady (2 newer stages x 3 ops; whole-stage counts are order-robust).
// ---------------------------------------------------------------------------
__global__ __launch_bounds__(256, 2) void gemm_out_kernel(
    const u16* __restrict__ Z,    // [8][512][4096]
    const u16* __restrict__ Dec,  // [8][512][4096]
    const float* __restrict__ bias,
    float* __restrict__ out) {    // [512][4096]
  __shared__ char sm[49152];      // 4 bufs x (A 8KB + B 4KB)
  const int lb = blockIdx.x;
  const int swz = ((lb & 7) << 5) | (lb >> 3);  // 256 % 8 == 0
  const int t = swz >> 5;
  const int rem = swz & 31;
  const int nb = rem >> 2, mb = rem & 3;
  const u16* At = Z + ((size_t)t << 21);
  const u16* Bt = Dec + ((size_t)t << 21);
  const int aRow0 = mb << 7, bCol0 = nb << 6;
  const int tid = threadIdx.x;
  const int wv = tid >> 6, ln = tid & 63;
  const int lr = ln & 15, lk = ln >> 4;
  const int wr = wv >> 1, wc = wv & 1;

  fx4 acc[4][2] = {};

  const int kswz = (((tid & 3) ^ ((tid >> 3) & 3)) << 3);
  const u16* Asrc = At + (size_t)(aRow0 + (tid >> 2)) * 4096 + kswz;
  const u16* Bsrc = Bt + (size_t)(bCol0 + (tid >> 2)) * 4096 + kswz;
  const int gr = (lr >> 1) & 3;
  const int aof = (wr * 64 + lr) * 64 + ((lk ^ gr) << 4);          // + m*1024
  const int bof = 8192 + (wc * 32 + lr) * 64 + ((lk ^ gr) << 4);   // + n*1024

#define STAGE_O(buf, kofs)                                                   \
  do {                                                                       \
    _Pragma("unroll")                                                        \
    for (int c = 0; c < 2; ++c)                                              \
      __builtin_amdgcn_global_load_lds(                                      \
          (gvoid*)(Asrc + (size_t)(c << 6) * 4096 + (kofs)),                 \
          (lvoid*)((buf) + c * 4096 + tid * 16), 16, 0, 0);                  \
    __builtin_amdgcn_global_load_lds((gvoid*)(Bsrc + (kofs)),                \
                                     (lvoid*)((buf) + 8192 + tid * 16), 16,  \
                                     0, 0);                                  \
  } while (0)

  char* b0 = sm;
  char* b1 = sm + 12288;
  char* b2 = sm + 24576;
  char* b3 = sm + 36864;
  STAGE_O(b0, 0);
  STAGE_O(b1, 32);
  STAGE_O(b2, 64);
  WAIT_VM6();                     // stage(0) complete; 1,2 in flight
  BARRIER();

#pragma unroll 1
  for (int kt = 0; kt < 128; ++kt) {
    if (kt + 3 < 128) STAGE_O(b3, (kt + 3) << 5);
    u32x4 af[4], bf[2];
#pragma unroll
    for (int m = 0; m < 4; ++m)
      af[m] = *(const u32x4*)(b0 + aof + m * 1024);
#pragma unroll
    for (int n = 0; n < 2; ++n)
      bf[n] = *(const u32x4*)(b0 + bof + n * 1024);
    WAIT_LGKM0();
    SFENCE();
#pragma unroll
    for (int m = 0; m < 4; ++m)
#pragma unroll
      for (int n = 0; n < 2; ++n)
        MFMA_BF16_16x16x32(acc[m][n], af[m], bf[n]);
    if (kt + 3 < 128) {
      WAIT_VM6();                 // stage(kt+1) done; kt+2, kt+3 in flight
    } else if (kt + 2 < 128) {
      WAIT_VM3();                 // kt = 125
    } else {
      WAIT_VM0();                 // kt = 126, 127
    }
    BARRIER();
    char* tmp = b0; b0 = b1; b1 = b2; b2 = b3; b3 = tmp;
  }

#pragma unroll
  for (int n = 0; n < 2; ++n) {
    const int colg = (t << 9) + bCol0 + wc * 32 + n * 16 + lr;
    const float bv = bias[colg];
#pragma unroll
    for (int m = 0; m < 4; ++m) {
      const int r0 = aRow0 + wr * 64 + m * 16 + lk * 4;
#pragma unroll
      for (int j = 0; j < 4; ++j)
        out[(size_t)(r0 + j) * 4096 + colg] = acc[m][n][j] + bv;
    }
  }
#undef STAGE_O
}

// ---------------------------------------------------------------------------
extern "C" void kernel_launch(void* const* d_in, const int* in_sizes, int n_in,
                              void* d_out, int out_size, void* d_ws, size_t ws_size,
                              hipStream_t stream) {
  const float* x       = (const float*)d_in[0];   // [512][4096]
  const float* cw      = (const float*)d_in[1];   // [16384][4096]
  const int*   indices = (const int*)d_in[2];     // [8][512][4]
  const float* rot     = (const float*)d_in[3];   // [8][4096][4096]
  const float* scales  = (const float*)d_in[4];   // [8]
  const float* bias    = (const float*)d_in[5];   // [4096]
  float* out = (float*)d_out;
  char* ws = (char*)d_ws;

  u16* xb  = (u16*)(ws);                          // 4 MiB
  u16* dec = (u16*)(ws + ((size_t)4 << 20));      // 32 MiB
  u16* z   = (u16*)(ws + ((size_t)36 << 20));     // 32 MiB

  cvtx_kernel<<<dim3(2048), dim3(256), 0, stream>>>(x, xb);
  fused_z_decode_kernel<<<dim3(1280), dim3(256), 0, stream>>>(
      xb, rot, z, cw, indices, scales, dec);
  gemm_out_kernel<<<dim3(256), dim3(256), 0, stream>>>(z, dec, bias, out);
}